// Round 20
// baseline (166.701 us; speedup 1.0000x reference)
//
#include <hip/hip_runtime.h>

typedef unsigned short ushort_t;
typedef short bf16x8 __attribute__((ext_vector_type(8)));
typedef float f32x4 __attribute__((ext_vector_type(4)));
typedef float f32x16 __attribute__((ext_vector_type(16)));

__device__ __forceinline__ unsigned f2bf(float f) {
  union { float f; unsigned u; } v; v.f = f;
  return (v.u + 0x7FFFu + ((v.u >> 16) & 1u)) >> 16;
}

__device__ __forceinline__ void gll16(const void* g, const void* l) {
  __builtin_amdgcn_global_load_lds(
      (const __attribute__((address_space(1))) void*)g,
      (__attribute__((address_space(3))) void*)l, 16, 0, 0);
}

// ---------------- f32 -> bf16 conversion ----------------
__global__ __launch_bounds__(256) void cvt_bf16(const float* __restrict__ src,
                                                ushort_t* __restrict__ dst, int n4) {
  int i = blockIdx.x * 256 + threadIdx.x;
  if (i >= n4) return;
  float4 v = ((const float4*)src)[i];
  uint2 o;
  o.x = f2bf(v.x) | (f2bf(v.y) << 16);
  o.y = f2bf(v.z) | (f2bf(v.w) << 16);
  ((uint2*)dst)[i] = o;
}

// ---------------- QKV GEMM + fused V-transpose (r18/r19 proven) ----------------
__global__ __launch_bounds__(256) void gemm_qkv(const ushort_t* __restrict__ A,
                                                const ushort_t* __restrict__ Bw,
                                                ushort_t* __restrict__ qk,
                                                ushort_t* __restrict__ VT) {
  __shared__ ushort_t As[128 * 64];
  __shared__ ushort_t Bs[128 * 64];
  const int tid = threadIdx.x;
  const int w = tid >> 6, ln = tid & 63;
  const int g = ln >> 4, lr = ln & 15;
  const int bx = blockIdx.x;
  const int swz = (bx & 7) * 192 + (bx >> 3);   // bijective (1536 % 8 == 0)
  const int nt = swz % 24, mt = swz / 24;
  const int m0 = mt * 128, n0 = nt * 128;
  const int wr = w >> 1, wc = w & 1;
  const float cscale = (nt < 8) ? 0.18033688f : 1.0f;  // Q pre-scale

  f32x4 acc[4][4] = {};

  for (int kt = 0; kt < 16; ++kt) {
#pragma unroll
    for (int q = 0; q < 4; ++q) {
      int chunk = w * 256 + q * 64 + ln;
      int r = chunk >> 3, c = chunk & 7;
      int cs = c ^ (r & 7);
      gll16(A + (size_t)(m0 + r) * 1024 + kt * 64 + cs * 8, As + chunk * 8);
      gll16(Bw + (size_t)(n0 + r) * 1024 + kt * 64 + cs * 8, Bs + chunk * 8);
    }
    __syncthreads();
#pragma unroll
    for (int ks = 0; ks < 2; ++ks) {
      bf16x8 af[4], bfr[4];
#pragma unroll
      for (int mi = 0; mi < 4; ++mi) {
        int row = wr * 64 + mi * 16 + lr;
        af[mi] = *(const bf16x8*)((const char*)As + row * 128 +
                                  ((g * 16 + ks * 64) ^ ((row & 7) << 4)));
      }
#pragma unroll
      for (int ni = 0; ni < 4; ++ni) {
        int row = wc * 64 + ni * 16 + lr;
        bfr[ni] = *(const bf16x8*)((const char*)Bs + row * 128 +
                                   ((g * 16 + ks * 64) ^ ((row & 7) << 4)));
      }
#pragma unroll
      for (int mi = 0; mi < 4; ++mi)
#pragma unroll
        for (int ni = 0; ni < 4; ++ni)
          acc[mi][ni] = __builtin_amdgcn_mfma_f32_16x16x32_bf16(af[mi], bfr[ni],
                                                                acc[mi][ni], 0, 0, 0);
    }
    __syncthreads();
  }

  if (nt < 16) {
#pragma unroll
    for (int mi = 0; mi < 4; ++mi)
#pragma unroll
      for (int ni = 0; ni < 4; ++ni)
#pragma unroll
        for (int r = 0; r < 4; ++r) {
          int row = m0 + wr * 64 + mi * 16 + g * 4 + r;
          int col = n0 + wc * 64 + ni * 16 + lr;
          qk[(size_t)row * 2048 + col] = (ushort_t)f2bf(acc[mi][ni][r] * cscale);
        }
  } else {
    // V: fused transpose to VT[(b*16+hh)*64+d][2048], token bits 2<->3 swapped.
    const int b = m0 >> 11;
    const int gp = ((g & 1) << 1) | (g >> 1);
#pragma unroll
    for (int mi = 0; mi < 4; ++mi) {
      int nbase = (m0 & 2047) + wr * 64 + mi * 16 + gp * 4;
#pragma unroll
      for (int ni = 0; ni < 4; ++ni) {
        int f = n0 - 2048 + wc * 64 + ni * 16 + lr;
        int hh = f >> 6, d = f & 63;
        uint2 o;
        o.x = f2bf(acc[mi][ni][0]) | (f2bf(acc[mi][ni][1]) << 16);
        o.y = f2bf(acc[mi][ni][2]) | (f2bf(acc[mi][ni][3]) << 16);
        *(uint2*)(VT + ((size_t)(b * 16 + hh) * 64 + d) * 2048 + nbase) = o;
      }
    }
  }
}

// ---------------- Flash attention, swapped-operand 32x32x16, static softmax ----
// r19 structure. VALU diet: (1) l via ones-MFMA again (VALU is now the top
// pipe at 41% vs matrix 35% -- r14's direction rule, r12's proven numerics);
// (2) S initialized through a persistent ZERO C-operand (kills 16 v_mov/iter).
__global__ __launch_bounds__(512) void attn2(const ushort_t* __restrict__ qk,
                                             const ushort_t* __restrict__ VT,
                                             float* __restrict__ out) {
  __shared__ ushort_t Ks[3][2048];
  __shared__ ushort_t Vs[3][2048];
  const int blk = blockIdx.x;
  const int bh = blk & 63, qt = blk >> 6;   // bh-major -> XCD L2 reuse
  const int b = bh >> 4, hh = bh & 15;
  const int tid = threadIdx.x;
  const int w = tid >> 6, l = tid & 63;
  const int q = l & 31, h = l >> 5;
  const int q0 = qt * 256 + w * 32;
  const int qsw = q & 7;

  // Q fragments (B-operand of swapped QK^T); Q pre-scaled by 0.125*log2(e)
  const ushort_t* qrow = qk + (size_t)(b * 2048 + q0 + q) * 2048 + hh * 64 + 8 * h;
  bf16x8 qf[4];
#pragma unroll
  for (int m = 0; m < 4; ++m) qf[m] = *(const bf16x8*)(qrow + 16 * m);

  // ones fragment for the l-accumulator MFMA (r12-proven)
  union { ushort_t s[8]; bf16x8 v; } vones;
#pragma unroll
  for (int i = 0; i < 8; ++i) vones.s[i] = 0x3F80;  // bf16 1.0

  // staging: threads 0-255 carry K, 256-511 carry V (wave-uniform split).
  const int st = tid & 255;
  const int rS = st >> 3, cS = st & 7;
  const int cL = cS ^ (rS & 7);
  const bool isK = tid < 256;
  const ushort_t* gsrc =
      isK ? qk + (size_t)(b * 2048 + rS) * 2048 + 1024 + hh * 64 + cL * 8
          : VT + (size_t)(bh * 64 + rS + 32 * (cL >> 2)) * 2048 + (cL & 3) * 8;
  const size_t gstep = isK ? (size_t)32 * 2048 : (size_t)32;
  ushort_t* lbase = isK ? &Ks[0][0] : &Vs[0][0];  // + buf*2048 + st*8

  f32x16 oacc0, oacc1, lacc, ZERO;
#pragma unroll
  for (int i = 0; i < 16; ++i) { oacc0[i] = 0.f; oacc1[i] = 0.f; lacc[i] = 0.f; ZERO[i] = 0.f; }

  // prologue: stage tiles 0 and 1 (1 load/thread each)
  gll16(gsrc, lbase + st * 8);
  gll16(gsrc + gstep, lbase + 2048 + st * 8);
  asm volatile("s_waitcnt vmcnt(1)" ::: "memory");
  __builtin_amdgcn_s_barrier();

  int cur = 0;
  for (int t = 0; t < 64; ++t) {
    int tn = t + 2; if (tn > 63) tn = 63;          // clamped prefetch (writes dead buffer)
    int bufn = cur + 2; if (bufn >= 3) bufn -= 3;
    gll16(gsrc + (size_t)tn * gstep, lbase + bufn * 2048 + st * 8);

    const ushort_t* KsB = Ks[cur];
    const ushort_t* VsB = Vs[cur];

    // ---- QK^T (swapped): S^T[k][q]; first MFMA consumes persistent ZERO ----
    __builtin_amdgcn_s_setprio(1);
    bf16x8 kf0 = *(const bf16x8*)(KsB + q * 64 + (((0 + h) ^ qsw) * 8));
    f32x16 S = __builtin_amdgcn_mfma_f32_32x32x16_bf16(kf0, qf[0], ZERO, 0, 0, 0);
#pragma unroll
    for (int m = 1; m < 4; ++m) {
      bf16x8 kf = *(const bf16x8*)(KsB + q * 64 + (((2 * m + h) ^ qsw) * 8));
      S = __builtin_amdgcn_mfma_f32_32x32x16_bf16(kf, qf[m], S, 0, 0, 0);
    }
    __builtin_amdgcn_s_setprio(0);

    // ---- static softmax: p = exp2(S); no max, no rescale, no l-tree ----
    float p[16];
#pragma unroll
    for (int i = 0; i < 16; ++i) p[i] = __builtin_amdgcn_exp2f(S[i]);

    // ---- pack P to bf16 PV fragments: fully lane-local ----
    union { unsigned u[4]; bf16x8 v; } pf0, pf1;
#pragma unroll
    for (int i = 0; i < 4; ++i)
      asm("v_cvt_pk_bf16_f32 %0, %1, %2"
          : "=v"(pf0.u[i]) : "v"(p[2 * i]), "v"(p[2 * i + 1]));
#pragma unroll
    for (int i = 0; i < 4; ++i)
      asm("v_cvt_pk_bf16_f32 %0, %1, %2"
          : "=v"(pf1.u[i]) : "v"(p[8 + 2 * i]), "v"(p[8 + 2 * i + 1]));

    // ---- V fragments ----
    bf16x8 vf0 = *(const bf16x8*)(VsB + q * 64 + (((0 + h) ^ qsw) * 8));
    bf16x8 vf1 = *(const bf16x8*)(VsB + q * 64 + (((2 + h) ^ qsw) * 8));
    bf16x8 vf2 = *(const bf16x8*)(VsB + q * 64 + (((4 + h) ^ qsw) * 8));
    bf16x8 vf3 = *(const bf16x8*)(VsB + q * 64 + (((6 + h) ^ qsw) * 8));

    // ---- PV (swapped) + l via ones-MFMA (k-sum crosses lanes in the pipe) ----
    __builtin_amdgcn_s_setprio(1);
    oacc0 = __builtin_amdgcn_mfma_f32_32x32x16_bf16(vf0, pf0.v, oacc0, 0, 0, 0);
    oacc0 = __builtin_amdgcn_mfma_f32_32x32x16_bf16(vf1, pf1.v, oacc0, 0, 0, 0);
    oacc1 = __builtin_amdgcn_mfma_f32_32x32x16_bf16(vf2, pf0.v, oacc1, 0, 0, 0);
    oacc1 = __builtin_amdgcn_mfma_f32_32x32x16_bf16(vf3, pf1.v, oacc1, 0, 0, 0);
    lacc  = __builtin_amdgcn_mfma_f32_32x32x16_bf16(vones.v, pf0.v, lacc, 0, 0, 0);
    lacc  = __builtin_amdgcn_mfma_f32_32x32x16_bf16(vones.v, pf1.v, lacc, 0, 0, 0);
    __builtin_amdgcn_s_setprio(0);

    // tile t+1 resident when the only outstanding load is this iter's (t+2)
    asm volatile("s_waitcnt vmcnt(1)" ::: "memory");
    __builtin_amdgcn_s_barrier();
    cur += 1; if (cur == 3) cur = 0;
  }

  // ---- epilogue: normalize by l (all lacc rows equal), store O^T columns ----
  float inv = 1.0f / lacc[0];
  float* orow = out + (size_t)(b * 2048 + q0 + q) * 1024 + hh * 64 + 4 * h;
#pragma unroll
  for (int rq = 0; rq < 4; ++rq) {
    float4 o0, o1;
    o0.x = oacc0[rq * 4 + 0] * inv; o0.y = oacc0[rq * 4 + 1] * inv;
    o0.z = oacc0[rq * 4 + 2] * inv; o0.w = oacc0[rq * 4 + 3] * inv;
    o1.x = oacc1[rq * 4 + 0] * inv; o1.y = oacc1[rq * 4 + 1] * inv;
    o1.z = oacc1[rq * 4 + 2] * inv; o1.w = oacc1[rq * 4 + 3] * inv;
    *(float4*)(orow + 8 * rq) = o0;
    *(float4*)(orow + 32 + 8 * rq) = o1;
  }
}

extern "C" void kernel_launch(void* const* d_in, const int* in_sizes, int n_in,
                              void* d_out, int out_size, void* d_ws, size_t ws_size,
                              hipStream_t stream) {
  const float* x = (const float*)d_in[0];
  const float* Wq = (const float*)d_in[1];
  float* out = (float*)d_out;
  char* ws = (char*)d_ws;

  ushort_t* xb = (ushort_t*)ws;                      // 16 MB: x bf16 [8192][1024]
  ushort_t* wb = (ushort_t*)(ws + 16777216);         // 6 MB:  W bf16 [3072][1024]
  ushort_t* qk = (ushort_t*)(ws + 23068672);         // 32 MB: Q|K bf16 [8192][2048]
  ushort_t* VT = (ushort_t*)(ws + 23068672 + 33554432);  // 16 MB: VT [64*64][2048]

  cvt_bf16<<<8192, 256, 0, stream>>>(x, xb, 8192 * 1024 / 4);
  cvt_bf16<<<3072, 256, 0, stream>>>(Wq, wb, 3072 * 1024 / 4);
  gemm_qkv<<<64 * 24, 256, 0, stream>>>(xb, wb, qk, VT);
  attn2<<<64 * 8, 512, 0, stream>>>(qk, VT, out);
}

// Round 21
// 162.224 us; speedup vs baseline: 1.0276x; 1.0276x over previous
//
#include <hip/hip_runtime.h>

typedef unsigned short ushort_t;
typedef short bf16x8 __attribute__((ext_vector_type(8)));
typedef float f32x4 __attribute__((ext_vector_type(4)));
typedef float f32x16 __attribute__((ext_vector_type(16)));

__device__ __forceinline__ unsigned f2bf(float f) {
  union { float f; unsigned u; } v; v.f = f;
  return (v.u + 0x7FFFu + ((v.u >> 16) & 1u)) >> 16;
}

__device__ __forceinline__ void gll16(const void* g, const void* l) {
  __builtin_amdgcn_global_load_lds(
      (const __attribute__((address_space(1))) void*)g,
      (__attribute__((address_space(3))) void*)l, 16, 0, 0);
}

// ---------------- f32 -> bf16 conversion, both inputs in one launch ----------
__global__ __launch_bounds__(256) void cvt_both(const float* __restrict__ x,
                                                const float* __restrict__ W,
                                                ushort_t* __restrict__ xb,
                                                ushort_t* __restrict__ wb) {
  int bid = blockIdx.x;
  const float* src;
  ushort_t* dst;
  int i;
  if (bid < 8192) { src = x; dst = xb; i = bid * 256 + threadIdx.x; }
  else            { src = W; dst = wb; i = (bid - 8192) * 256 + threadIdx.x; }
  float4 v = ((const float4*)src)[i];
  uint2 o;
  o.x = f2bf(v.x) | (f2bf(v.y) << 16);
  o.y = f2bf(v.z) | (f2bf(v.w) << 16);
  ((uint2*)dst)[i] = o;
}

// ---------------- QKV GEMM + fused V-transpose (r18/r19 proven) ----------------
// C = A[8192][1024] * W[3072][1024]^T. Q/K thirds (nt<16) -> qk[8192][2048]
// (Q pre-scaled by 0.125*log2(e) for the static softmax). V third (nt>=16)
// written directly to VT[bh*64+d][2048] with the kv bit2<->3 permutation.
// XCD swizzle: 8 contiguous mt-rows per XCD (A-panels L2-resident).
__global__ __launch_bounds__(256) void gemm_qkv(const ushort_t* __restrict__ A,
                                                const ushort_t* __restrict__ Bw,
                                                ushort_t* __restrict__ qk,
                                                ushort_t* __restrict__ VT) {
  __shared__ ushort_t As[128 * 64];
  __shared__ ushort_t Bs[128 * 64];
  const int tid = threadIdx.x;
  const int w = tid >> 6, ln = tid & 63;
  const int g = ln >> 4, lr = ln & 15;
  const int bx = blockIdx.x;
  const int swz = (bx & 7) * 192 + (bx >> 3);   // bijective (1536 % 8 == 0)
  const int nt = swz % 24, mt = swz / 24;
  const int m0 = mt * 128, n0 = nt * 128;
  const int wr = w >> 1, wc = w & 1;
  const float cscale = (nt < 8) ? 0.18033688f : 1.0f;  // Q pre-scale

  f32x4 acc[4][4] = {};

  for (int kt = 0; kt < 16; ++kt) {
#pragma unroll
    for (int q = 0; q < 4; ++q) {
      int chunk = w * 256 + q * 64 + ln;
      int r = chunk >> 3, c = chunk & 7;
      int cs = c ^ (r & 7);
      gll16(A + (size_t)(m0 + r) * 1024 + kt * 64 + cs * 8, As + chunk * 8);
      gll16(Bw + (size_t)(n0 + r) * 1024 + kt * 64 + cs * 8, Bs + chunk * 8);
    }
    __syncthreads();
#pragma unroll
    for (int ks = 0; ks < 2; ++ks) {
      bf16x8 af[4], bfr[4];
#pragma unroll
      for (int mi = 0; mi < 4; ++mi) {
        int row = wr * 64 + mi * 16 + lr;
        af[mi] = *(const bf16x8*)((const char*)As + row * 128 +
                                  ((g * 16 + ks * 64) ^ ((row & 7) << 4)));
      }
#pragma unroll
      for (int ni = 0; ni < 4; ++ni) {
        int row = wc * 64 + ni * 16 + lr;
        bfr[ni] = *(const bf16x8*)((const char*)Bs + row * 128 +
                                   ((g * 16 + ks * 64) ^ ((row & 7) << 4)));
      }
#pragma unroll
      for (int mi = 0; mi < 4; ++mi)
#pragma unroll
        for (int ni = 0; ni < 4; ++ni)
          acc[mi][ni] = __builtin_amdgcn_mfma_f32_16x16x32_bf16(af[mi], bfr[ni],
                                                                acc[mi][ni], 0, 0, 0);
    }
    __syncthreads();
  }

  if (nt < 16) {
#pragma unroll
    for (int mi = 0; mi < 4; ++mi)
#pragma unroll
      for (int ni = 0; ni < 4; ++ni)
#pragma unroll
        for (int r = 0; r < 4; ++r) {
          int row = m0 + wr * 64 + mi * 16 + g * 4 + r;
          int col = n0 + wc * 64 + ni * 16 + lr;
          qk[(size_t)row * 2048 + col] = (ushort_t)f2bf(acc[mi][ni][r] * cscale);
        }
  } else {
    // V: fused transpose to VT[(b*16+hh)*64+d][2048], token bits 2<->3 swapped.
    const int b = m0 >> 11;
    const int gp = ((g & 1) << 1) | (g >> 1);
#pragma unroll
    for (int mi = 0; mi < 4; ++mi) {
      int nbase = (m0 & 2047) + wr * 64 + mi * 16 + gp * 4;
#pragma unroll
      for (int ni = 0; ni < 4; ++ni) {
        int f = n0 - 2048 + wc * 64 + ni * 16 + lr;
        int hh = f >> 6, d = f & 63;
        uint2 o;
        o.x = f2bf(acc[mi][ni][0]) | (f2bf(acc[mi][ni][1]) << 16);
        o.y = f2bf(acc[mi][ni][2]) | (f2bf(acc[mi][ni][3]) << 16);
        *(uint2*)(VT + ((size_t)(b * 16 + hh) * 64 + d) * 2048 + nbase) = o;
      }
    }
  }
}

// ---------------- Flash attention (r19-exact: best proven, 83.2 us) ----------
__global__ __launch_bounds__(512) void attn2(const ushort_t* __restrict__ qk,
                                             const ushort_t* __restrict__ VT,
                                             float* __restrict__ out) {
  __shared__ ushort_t Ks[3][2048];
  __shared__ ushort_t Vs[3][2048];
  const int blk = blockIdx.x;
  const int bh = blk & 63, qt = blk >> 6;   // bh-major -> XCD L2 reuse
  const int b = bh >> 4, hh = bh & 15;
  const int tid = threadIdx.x;
  const int w = tid >> 6, l = tid & 63;
  const int q = l & 31, h = l >> 5;
  const int q0 = qt * 256 + w * 32;
  const int qsw = q & 7;

  // Q fragments (B-operand of swapped QK^T); Q pre-scaled by 0.125*log2(e)
  const ushort_t* qrow = qk + (size_t)(b * 2048 + q0 + q) * 2048 + hh * 64 + 8 * h;
  bf16x8 qf[4];
#pragma unroll
  for (int m = 0; m < 4; ++m) qf[m] = *(const bf16x8*)(qrow + 16 * m);

  // staging: threads 0-255 carry K, 256-511 carry V (wave-uniform split).
  const int st = tid & 255;
  const int rS = st >> 3, cS = st & 7;
  const int cL = cS ^ (rS & 7);
  const bool isK = tid < 256;
  const ushort_t* gsrc =
      isK ? qk + (size_t)(b * 2048 + rS) * 2048 + 1024 + hh * 64 + cL * 8
          : VT + (size_t)(bh * 64 + rS + 32 * (cL >> 2)) * 2048 + (cL & 3) * 8;
  const size_t gstep = isK ? (size_t)32 * 2048 : (size_t)32;
  ushort_t* lbase = isK ? &Ks[0][0] : &Vs[0][0];  // + buf*2048 + st*8

  f32x16 oacc0, oacc1;
#pragma unroll
  for (int i = 0; i < 16; ++i) { oacc0[i] = 0.f; oacc1[i] = 0.f; }
  float l_run = 0.f;

  // prologue: stage tiles 0 and 1 (1 load/thread each)
  gll16(gsrc, lbase + st * 8);
  gll16(gsrc + gstep, lbase + 2048 + st * 8);
  asm volatile("s_waitcnt vmcnt(1)" ::: "memory");
  __builtin_amdgcn_s_barrier();

  int cur = 0;
  for (int t = 0; t < 64; ++t) {
    int tn = t + 2; if (tn > 63) tn = 63;          // clamped prefetch (writes dead buffer)
    int bufn = cur + 2; if (bufn >= 3) bufn -= 3;
    gll16(gsrc + (size_t)tn * gstep, lbase + bufn * 2048 + st * 8);

    const ushort_t* KsB = Ks[cur];
    const ushort_t* VsB = Vs[cur];

    // ---- QK^T (swapped): S^T[k][q], S pre-scaled via Q ----
    f32x16 S;
#pragma unroll
    for (int i = 0; i < 16; ++i) S[i] = 0.f;
    __builtin_amdgcn_s_setprio(1);
#pragma unroll
    for (int m = 0; m < 4; ++m) {
      bf16x8 kf = *(const bf16x8*)(KsB + q * 64 + (((2 * m + h) ^ qsw) * 8));
      S = __builtin_amdgcn_mfma_f32_32x32x16_bf16(kf, qf[m], S, 0, 0, 0);
    }
    __builtin_amdgcn_s_setprio(0);

    // ---- static softmax: p = exp2(S); l via VALU tree ----
    float p[16];
#pragma unroll
    for (int i = 0; i < 16; ++i) p[i] = __builtin_amdgcn_exp2f(S[i]);
    float s0 = (p[0] + p[1]) + (p[2] + p[3]);
    float s1 = (p[4] + p[5]) + (p[6] + p[7]);
    float s2 = (p[8] + p[9]) + (p[10] + p[11]);
    float s3 = (p[12] + p[13]) + (p[14] + p[15]);
    float ls = (s0 + s1) + (s2 + s3);
    ls += __shfl_xor(ls, 32, 64);
    l_run += ls;

    // ---- pack P to bf16 PV fragments: fully lane-local ----
    union { unsigned u[4]; bf16x8 v; } pf0, pf1;
#pragma unroll
    for (int i = 0; i < 4; ++i)
      asm("v_cvt_pk_bf16_f32 %0, %1, %2"
          : "=v"(pf0.u[i]) : "v"(p[2 * i]), "v"(p[2 * i + 1]));
#pragma unroll
    for (int i = 0; i < 4; ++i)
      asm("v_cvt_pk_bf16_f32 %0, %1, %2"
          : "=v"(pf1.u[i]) : "v"(p[8 + 2 * i]), "v"(p[8 + 2 * i + 1]));

    // ---- V fragments ----
    bf16x8 vf0 = *(const bf16x8*)(VsB + q * 64 + (((0 + h) ^ qsw) * 8));
    bf16x8 vf1 = *(const bf16x8*)(VsB + q * 64 + (((2 + h) ^ qsw) * 8));
    bf16x8 vf2 = *(const bf16x8*)(VsB + q * 64 + (((4 + h) ^ qsw) * 8));
    bf16x8 vf3 = *(const bf16x8*)(VsB + q * 64 + (((6 + h) ^ qsw) * 8));

    // ---- PV (swapped): O^T[d][q] += V^T[d][kv] * P^T[kv][q] ----
    __builtin_amdgcn_s_setprio(1);
    oacc0 = __builtin_amdgcn_mfma_f32_32x32x16_bf16(vf0, pf0.v, oacc0, 0, 0, 0);
    oacc0 = __builtin_amdgcn_mfma_f32_32x32x16_bf16(vf1, pf1.v, oacc0, 0, 0, 0);
    oacc1 = __builtin_amdgcn_mfma_f32_32x32x16_bf16(vf2, pf0.v, oacc1, 0, 0, 0);
    oacc1 = __builtin_amdgcn_mfma_f32_32x32x16_bf16(vf3, pf1.v, oacc1, 0, 0, 0);
    __builtin_amdgcn_s_setprio(0);

    // tile t+1 resident when the only outstanding load is this iter's (t+2)
    asm volatile("s_waitcnt vmcnt(1)" ::: "memory");
    __builtin_amdgcn_s_barrier();
    cur += 1; if (cur == 3) cur = 0;
  }

  // ---- epilogue: normalize by l, store O^T columns (16B chunks) ----
  float inv = 1.0f / l_run;
  float* orow = out + (size_t)(b * 2048 + q0 + q) * 1024 + hh * 64 + 4 * h;
#pragma unroll
  for (int rq = 0; rq < 4; ++rq) {
    float4 o0, o1;
    o0.x = oacc0[rq * 4 + 0] * inv; o0.y = oacc0[rq * 4 + 1] * inv;
    o0.z = oacc0[rq * 4 + 2] * inv; o0.w = oacc0[rq * 4 + 3] * inv;
    o1.x = oacc1[rq * 4 + 0] * inv; o1.y = oacc1[rq * 4 + 1] * inv;
    o1.z = oacc1[rq * 4 + 2] * inv; o1.w = oacc1[rq * 4 + 3] * inv;
    *(float4*)(orow + 8 * rq) = o0;
    *(float4*)(orow + 32 + 8 * rq) = o1;
  }
}

extern "C" void kernel_launch(void* const* d_in, const int* in_sizes, int n_in,
                              void* d_out, int out_size, void* d_ws, size_t ws_size,
                              hipStream_t stream) {
  const float* x = (const float*)d_in[0];
  const float* Wq = (const float*)d_in[1];
  float* out = (float*)d_out;
  char* ws = (char*)d_ws;

  ushort_t* xb = (ushort_t*)ws;                      // 16 MB: x bf16 [8192][1024]
  ushort_t* wb = (ushort_t*)(ws + 16777216);         // 6 MB:  W bf16 [3072][1024]
  ushort_t* qk = (ushort_t*)(ws + 23068672);         // 32 MB: Q|K bf16 [8192][2048]
  ushort_t* VT = (ushort_t*)(ws + 23068672 + 33554432);  // 16 MB: VT [64*64][2048]

  cvt_both<<<8192 + 3072, 256, 0, stream>>>(x, Wq, xb, wb);
  gemm_qkv<<<64 * 24, 256, 0, stream>>>(xb, wb, qk, VT);
  attn2<<<64 * 8, 512, 0, stream>>>(qk, VT, out);
}